// Round 6
// baseline (500.673 us; speedup 1.0000x reference)
//
#include <hip/hip_runtime.h>

// TT-chain: N=65536, L=128, D=4, R=8, O=2.
//   m = x[n,0] @ core_first[0]
//   for c in 0..125: m[l] = sum_{k,j} m[k]*cm[c,k,j,l]*x[n,c+1,j]
//   out[n,:] = sum_{k,j} m[k]*cl[k,j,:]*x[n,127,j]
// cm[:, :, 3, :] == I -> j=3 term is x.w*m[l]. Full fp32 (exact).
//
// R11 design: 4 LANES PER SAMPLE (quad-split of the l dimension).
//   R5-R10 post-mortem: with 1 lane = 1 sample, all 64 lanes need the
//   same 192 core floats per step; every broadcast mechanism charges a
//   full issue slot or serialized latency per value (readlane: R9 116us;
//   s_load: R6 257us; LDS bcast: R5 140us; fp16 readlane: R10 cvt spam
//   163us), and occupancy is pinned at 1 wave/SIMD so nothing hides.
//   R11: lane i of a quad owns l in {i, i+4}. Cores become PER-LANE data
//   (48 floats/step/lane, 12 coalesced dwordx4, L1/L2-hot) -> no
//   broadcast instructions at all. The 8-wide state m is gathered with
//   8 v_mov_dpp quad_perm broadcasts (full-rate VALU, no LDS/SGPR).
//   Adjacent (l, l+4) pairs -> float2 math -> v_pk_fma_f32 halves FMA
//   slots. 16 samples/wave -> 4096 waves -> 4 waves/SIMD: cross-wave
//   latency hiding at last. A-half cores (k<4) double-buffered one step
//   ahead; B-half (k>=4) loaded at step top, consumed late-step; x
//   prefetched 3 rows deep (covers ~900cy HBM miss).
//
// Cycle model per lane-step: 8 dpp(mk) + 4 dpp(x-splat) + ~33 pk ops +
// 13 loads + ~8 misc ~ 66 instr ~ 132 cyc. Per SIMD: 4 waves x 126 x
// 132 ~ 66k cyc ~ 28 us. HBM: 128 MB x over ~30 us ~ 4.3 TB/s < roof.

#define NTHREADS 256
#define SAMPLES_PER_BLOCK 64   // 4 waves x 16 quads

typedef float f2 __attribute__((ext_vector_type(2)));

#define QBCAST(k) ((k) | ((k) << 2) | ((k) << 4) | ((k) << 6))

template <int CTRL>
__device__ __forceinline__ float dppf(float v) {
    return __builtin_bit_cast(float,
        __builtin_amdgcn_mov_dpp(__builtin_bit_cast(int, v), CTRL, 0xf, 0xf, false));
}

// Pack cm[126,8,4,8] -> cpk[c][i][k][j][h] with l = i + 4*h:
// slab of 48 dwords per (c, lane-in-quad i); dword w = k*6 + j*2 + h.
// +192-dword zero pad (step-125 prefetch of "step 126" A-half).
__global__ __launch_bounds__(NTHREADS) void pack_cores_q(
    const float* __restrict__ cm, float* __restrict__ cpk)
{
    int t = blockIdx.x * NTHREADS + threadIdx.x;
    if (t >= 126 * 192 + 192) return;
    if (t >= 126 * 192) { cpk[t] = 0.f; return; }   // pad
    int c = t / 192, r = t % 192;
    int i = r / 48,  w = r % 48;
    int k = w / 6,   jj = w % 6;
    int j = jj >> 1, h = jj & 1;
    cpk[t] = cm[c * 256 + k * 32 + j * 8 + (i + 4 * h)];
}

// pair (l=i, l=i+4) for quad q = k*3+j from a 6-float4 buffer (q literal)
#define PF(BUF, q) ((q) & 1 ? f2{BUF[(q) >> 1].z, BUF[(q) >> 1].w} \
                            : f2{BUF[(q) >> 1].x, BUF[(q) >> 1].y})

#define KBODY(MKSRC, BUF, K) {                                   \
    const float mk = dppf<QBCAST(K)>(MKSRC);                     \
    f2 t = PF(BUF, (K)*3 + 0) * xx;                              \
    t = PF(BUF, (K)*3 + 1) * xy + t;                             \
    t = PF(BUF, (K)*3 + 2) * xz + t;                             \
    nm = f2{mk, mk} * t + nm; }

#define STEPQ(A)  {                                              \
    const float x0 = dppf<QBCAST(0)>(xc);                        \
    const float x1 = dppf<QBCAST(1)>(xc);                        \
    const float x2 = dppf<QBCAST(2)>(xc);                        \
    const float x3 = dppf<QBCAST(3)>(xc);                        \
    const f2 xx = {x0, x0}, xy = {x1, x1}, xz = {x2, x2};        \
    f2 nm = f2{x3, x3} * m2;                                     \
    KBODY(m2.x, A, 0) KBODY(m2.x, A, 1)                          \
    KBODY(m2.x, A, 2) KBODY(m2.x, A, 3)                          \
    KBODY(m2.y, Bb, 0) KBODY(m2.y, Bb, 1)                        \
    KBODY(m2.y, Bb, 2) KBODY(m2.y, Bb, 3)                        \
    m2 = nm; }

__global__ __launch_bounds__(NTHREADS, 4) void tt_chain_q(
    const float* __restrict__ x,          // [N,128,4]
    const float* __restrict__ cpk,        // packed cores (+192-dword pad)
    const float* __restrict__ cf,         // [1,4,8]
    const float* __restrict__ cl,         // [8,4,2]
    float* __restrict__ out)              // [N,2]
{
    const int tid = threadIdx.x;
    const int i   = tid & 3;                                   // lane-in-quad
    const int n   = blockIdx.x * SAMPLES_PER_BLOCK + (tid >> 2);

    const float* __restrict__ xF = x + (size_t)n * 512;        // dwords
    const float4* __restrict__ cpk4 = reinterpret_cast<const float4*>(cpk);
    const int slab4 = i * 12;          // float4 offset of lane's slab

    // ---- prologue ----
    float4 A0[6], A1[6], Bb[6];
    #pragma unroll
    for (int q = 0; q < 6; ++q) A0[q] = cpk4[slab4 + q];       // step 0, k<4

    // x component pipeline (lane's component i): rows 1,2,3
    float xc  = xF[4 + i];
    float xn1 = xF[8 + i];
    float xn2 = xF[12 + i];

    // m init from row 0: m[l] = sum_j x0_j * cf[j*8+l], l = i and i+4
    const float4 xr0 = reinterpret_cast<const float4*>(xF)[0];
    f2 m2;
    m2.x = fmaf(cf[i],      xr0.x, fmaf(cf[8 + i],  xr0.y,
           fmaf(cf[16 + i], xr0.z, cf[24 + i] * xr0.w)));
    m2.y = fmaf(cf[4 + i],  xr0.x, fmaf(cf[12 + i], xr0.y,
           fmaf(cf[20 + i], xr0.z, cf[28 + i] * xr0.w)));

    // ---- 63 double-steps: c = 0..125 ----
    #pragma unroll 1
    for (int t = 0; t < 63; ++t) {
        const int c0 = 2 * t;
        {   // step c0: compute from A0, prefetch A1 for c0+1
            const int cb = c0 * 48 + slab4;
            #pragma unroll
            for (int q = 0; q < 6; ++q) Bb[q] = cpk4[cb + 6 + q];    // k>=4, this step
            #pragma unroll
            for (int q = 0; q < 6; ++q) A1[q] = cpk4[cb + 48 + q];   // k<4, next step
            const int tx = (c0 + 4 < 128) ? (c0 + 4) * 4 : 508;
            const float xload = xF[tx + i];
            STEPQ(A0)
            xc = xn1; xn1 = xn2; xn2 = xload;
        }
        {   // step c0+1: compute from A1, prefetch A0 for c0+2
            const int cb = (c0 + 1) * 48 + slab4;
            #pragma unroll
            for (int q = 0; q < 6; ++q) Bb[q] = cpk4[cb + 6 + q];
            #pragma unroll
            for (int q = 0; q < 6; ++q) A0[q] = cpk4[cb + 48 + q];   // c=126 hits pad
            const int tx = (c0 + 5 < 128) ? (c0 + 5) * 4 : 508;
            const float xload = xF[tx + i];
            STEPQ(A1)
            xc = xn1; xn1 = xn2; xn2 = xload;
        }
    }

    // ---- epilogue: xc now = row 127 component i ----
    {
        const float e0 = dppf<QBCAST(0)>(xc);
        const float e1 = dppf<QBCAST(1)>(xc);
        const float e2 = dppf<QBCAST(2)>(xc);
        const float e3 = dppf<QBCAST(3)>(xc);
        const float xj[4] = { e0, e1, e2, e3 };
        // lane's partial over its two k's (k=i and k=i+4)
        float o0 = 0.f, o1 = 0.f;
        #pragma unroll
        for (int j = 0; j < 4; ++j) {
            o0 += xj[j] * (m2.x * cl[i * 8 + j * 2 + 0] +
                           m2.y * cl[(i + 4) * 8 + j * 2 + 0]);
            o1 += xj[j] * (m2.x * cl[i * 8 + j * 2 + 1] +
                           m2.y * cl[(i + 4) * 8 + j * 2 + 1]);
        }
        // quad reduction (sum over the 4 lanes of the sample)
        o0 += dppf<0xB1>(o0);   // quad_perm(1,0,3,2)
        o0 += dppf<0x4E>(o0);   // quad_perm(2,3,0,1)
        o1 += dppf<0xB1>(o1);
        o1 += dppf<0x4E>(o1);
        if (i == 0)
            reinterpret_cast<float2*>(out)[n] = make_float2(o0, o1);
    }
}

extern "C" void kernel_launch(void* const* d_in, const int* in_sizes, int n_in,
                              void* d_out, int out_size, void* d_ws, size_t ws_size,
                              hipStream_t stream) {
    const float* x  = (const float*)d_in[0];   // [N,128,4]
    const float* cf = (const float*)d_in[1];   // [1,4,8]
    const float* cm = (const float*)d_in[2];   // [126,8,4,8]
    const float* cl = (const float*)d_in[3];   // [8,4,2]
    float* out = (float*)d_out;                // [N,2]

    const int N = in_sizes[0] / (128 * 4);

    // packed fp32 cores: (126*192 + 192) dwords = 97536 B in workspace
    float* cpk = (float*)d_ws;

    pack_cores_q<<<(126 * 192 + 192 + NTHREADS - 1) / NTHREADS, NTHREADS, 0, stream>>>(cm, cpk);

    tt_chain_q<<<N / SAMPLES_PER_BLOCK, NTHREADS, 0, stream>>>(x, cpk, cf, cl, out);
}